// Round 10
// baseline (616.029 us; speedup 1.0000x reference)
//
#include <hip/hip_runtime.h>
#include <hip/hip_bf16.h>

#define NN 64
#define CC 512
#define MM 1600
#define KK 64
#define EPSF 1e-12f
#define REP 6   // diagnostic: repeat heavy phases so rocprof surfaces them

typedef __attribute__((ext_vector_type(4))) float f32x4;
typedef __attribute__((ext_vector_type(8))) short bf16x8;

// hardware RNE f32->bf16
__device__ inline unsigned short f2bf(float f) {
    __hip_bfloat16 b = __float2bfloat16(f);
    unsigned short u;
    __builtin_memcpy(&u, &b, sizeof(u));
    return u;
}

// ---------------------------------------------------------------------------
// w -> bf16
// ---------------------------------------------------------------------------
__global__ __launch_bounds__(256) void wconv_kernel(
    const float* __restrict__ w, unsigned short* __restrict__ wb)
{
    const int i = (blockIdx.x * 256 + threadIdx.x) * 8;
    float4 a = *(const float4*)(w + i);
    float4 b = *(const float4*)(w + i + 4);
    ushort4 u0, u1;
    u0.x = f2bf(a.x); u0.y = f2bf(a.y); u0.z = f2bf(a.z); u0.w = f2bf(a.w);
    u1.x = f2bf(b.x); u1.y = f2bf(b.y); u1.z = f2bf(b.z); u1.w = f2bf(b.w);
    *(ushort4*)(wb + i) = u0;
    *(ushort4*)(wb + i + 4) = u1;
}

// ---------------------------------------------------------------------------
// fused1 (R9 + REP diagnostic loop around the load+MFMA phase)
// ---------------------------------------------------------------------------
__global__ __launch_bounds__(256) void fused1_kernel(
    const float* __restrict__ x, const unsigned short* __restrict__ wb,
    const float* __restrict__ bias,
    unsigned short* __restrict__ ap, float* __restrict__ asum_part)
{
    __shared__ float als[64][68];   // a (unscaled), [k][m]
    __shared__ float rn_s[64];

    const int t  = threadIdx.x;
    const int n  = blockIdx.y;
    const int mt = blockIdx.x;
    const int m0 = mt * 64;
    const int wv   = t >> 6;
    const int lane = t & 63;
    const int g    = lane >> 4;   // 0..3
    const int lr   = lane & 15;
    const int m_lane = m0 + wv * 16 + lr;

    f32x4 acc[4];
    float ss;
    const float* xcol = x + (size_t)n * CC * MM + m_lane;
    const unsigned short* wrow = wb + g * 8;

    #pragma unroll 1
    for (int rep = 0; rep < REP; ++rep) {
        #pragma unroll
        for (int kt = 0; kt < 4; ++kt) acc[kt] = (f32x4){0.f, 0.f, 0.f, 0.f};
        ss = 0.f;
        #pragma unroll 4
        for (int cs = 0; cs < 16; ++cs) {
            const int cbase = cs * 32 + g * 8;
            float xv[8];
            #pragma unroll
            for (int j = 0; j < 8; ++j) xv[j] = xcol[(size_t)(cbase + j) * MM];
            bf16x8 bfrag;
            #pragma unroll
            for (int j = 0; j < 8; ++j) {
                ss += xv[j] * xv[j];
                bfrag[j] = (short)f2bf(xv[j]);
            }
            #pragma unroll
            for (int kt = 0; kt < 4; ++kt) {
                bf16x8 afrag = *(const bf16x8*)(wrow + (kt * 16 + lr) * CC + cs * 32);
                acc[kt] = __builtin_amdgcn_mfma_f32_16x16x32_bf16(afrag, bfrag, acc[kt], 0, 0, 0);
            }
        }
    }

    ss += __shfl_xor(ss, 16);
    ss += __shfl_xor(ss, 32);
    const float rnm = 1.0f / fmaxf(sqrtf(ss), EPSF);
    if (g == 0) rn_s[wv * 16 + lr] = rnm;

    float l[16];
    #pragma unroll
    for (int kt = 0; kt < 4; ++kt) {
        float4 bb = *(const float4*)(bias + kt * 16 + g * 4);
        l[kt * 4 + 0] = acc[kt][0] * rnm + bb.x;
        l[kt * 4 + 1] = acc[kt][1] * rnm + bb.y;
        l[kt * 4 + 2] = acc[kt][2] * rnm + bb.z;
        l[kt * 4 + 3] = acc[kt][3] * rnm + bb.w;
    }
    float mx = l[0];
    #pragma unroll
    for (int i = 1; i < 16; ++i) mx = fmaxf(mx, l[i]);
    mx = fmaxf(mx, __shfl_xor(mx, 16));
    mx = fmaxf(mx, __shfl_xor(mx, 32));
    float s = 0.f;
    #pragma unroll
    for (int i = 0; i < 16; ++i) { l[i] = __expf(l[i] - mx); s += l[i]; }
    s += __shfl_xor(s, 16);
    s += __shfl_xor(s, 32);
    const float inv = 1.0f / s;
    #pragma unroll
    for (int kt = 0; kt < 4; ++kt)
        #pragma unroll
        for (int r = 0; r < 4; ++r)
            als[kt * 16 + g * 4 + r][wv * 16 + lr] = l[kt * 4 + r] * inv;
    __syncthreads();

    {
        const int k = t >> 2, q = t & 3;
        float spart = 0.f;
        unsigned short ub[16];
        #pragma unroll
        for (int i = 0; i < 16; ++i) {
            float a = als[k][q * 16 + i];
            spart += a;
            ub[i] = f2bf(a * rn_s[q * 16 + i]);
        }
        unsigned short* dst = ap + ((size_t)(n * KK + k)) * MM + m0 + q * 16;
        *(uint4*)dst = *(uint4*)&ub[0];
        *(uint4*)(dst + 8) = *(uint4*)&ub[8];
        spart += __shfl_xor(spart, 1);
        spart += __shfl_xor(spart, 2);
        if (q == 0) asum_part[((size_t)(n * 25 + mt)) * 64 + k] = spart;
    }
}

// ---------------------------------------------------------------------------
// aggm (R9 + REP diagnostic loop around the whole mc loop)
// ---------------------------------------------------------------------------
__global__ __launch_bounds__(256) void aggm_kernel(
    const float* __restrict__ x, const unsigned short* __restrict__ ap,
    float* __restrict__ aggp)
{
    __shared__ __attribute__((aligned(16))) unsigned short als2[64][72];
    const int t    = threadIdx.x;
    const int ct   = blockIdx.x;
    const int mh   = blockIdx.y;
    const int n    = blockIdx.z;
    const int wv   = t >> 6;
    const int lane = t & 63;
    const int g    = lane >> 4;
    const int lr   = lane & 15;
    const int c_w  = ct * 64 + wv * 16;

    f32x4 acc[4];
    const int ks = t >> 2, qs = t & 3;   // staging coords
    const float* xrow = x + ((size_t)(n * CC + c_w + lr)) * MM;

    const int mc_beg = mh ? 832 : 0;     // 13 tiles | 12 tiles
    const int mc_end = mh ? MM : 832;

    #pragma unroll 1
    for (int rep = 0; rep < REP; ++rep) {
        #pragma unroll
        for (int kt = 0; kt < 4; ++kt) acc[kt] = (f32x4){0.f, 0.f, 0.f, 0.f};

        for (int mc = mc_beg; mc < mc_end; mc += 64) {
            __syncthreads();
            {
                const unsigned short* src = ap + ((size_t)(n * KK + ks)) * MM + mc + qs * 16;
                uint4 w0 = *(const uint4*)src;
                uint4 w1 = *(const uint4*)(src + 8);
                *(uint4*)&als2[ks][qs * 16] = w0;
                *(uint4*)&als2[ks][qs * 16 + 8] = w1;
            }
            __syncthreads();
            #pragma unroll
            for (int msi = 0; msi < 2; ++msi) {
                const int ms = msi * 32;
                float4 v0 = *(const float4*)(xrow + mc + ms + g * 8);
                float4 v1 = *(const float4*)(xrow + mc + ms + g * 8 + 4);
                bf16x8 bf;
                bf[0] = (short)f2bf(v0.x); bf[1] = (short)f2bf(v0.y);
                bf[2] = (short)f2bf(v0.z); bf[3] = (short)f2bf(v0.w);
                bf[4] = (short)f2bf(v1.x); bf[5] = (short)f2bf(v1.y);
                bf[6] = (short)f2bf(v1.z); bf[7] = (short)f2bf(v1.w);
                #pragma unroll
                for (int kt = 0; kt < 4; ++kt) {
                    bf16x8 af = *(const bf16x8*)&als2[kt * 16 + lr][ms + g * 8];
                    acc[kt] = __builtin_amdgcn_mfma_f32_16x16x32_bf16(af, bf, acc[kt], 0, 0, 0);
                }
            }
        }
    }
    #pragma unroll
    for (int kt = 0; kt < 4; ++kt)
        #pragma unroll
        for (int r = 0; r < 4; ++r) {
            const int k = kt * 16 + g * 4 + r;
            aggp[((size_t)((mh * NN + n) * KK + k)) * CC + c_w + lr] = acc[kt][r];
        }
}

// ---------------------------------------------------------------------------
// vlad = (agg0+agg1) - asum*cent, intra-normalize over C, global scale 0.125
// ---------------------------------------------------------------------------
__global__ __launch_bounds__(256) void vlad_kernel(
    const float* __restrict__ aggp, const float* __restrict__ asum_part,
    const float* __restrict__ cent, float* __restrict__ out)
{
    __shared__ float wsum[4];
    __shared__ float sinv;
    const int nk = blockIdx.x;          // n*64 + k
    const int n = nk >> 6, k = nk & 63;
    const int t = threadIdx.x;
    const int u = t & 63;
    const size_t half = (size_t)NN * KK * CC;

    float pa = (u < 25) ? asum_part[((size_t)(n * 25 + u)) * 64 + k] : 0.f;
    #pragma unroll
    for (int o = 32; o > 0; o >>= 1) pa += __shfl_xor(pa, o);
    const float s = pa;

    float2 a0 = *(const float2*)(aggp + (size_t)nk * CC + 2 * t);
    float2 a1 = *(const float2*)(aggp + half + (size_t)nk * CC + 2 * t);
    float2 cv = *(const float2*)(cent + (size_t)k * CC + 2 * t);
    float v0 = (a0.x + a1.x) - s * cv.x;
    float v1 = (a0.y + a1.y) - s * cv.y;
    float ss = v0 * v0 + v1 * v1;
    #pragma unroll
    for (int o = 32; o > 0; o >>= 1) ss += __shfl_down(ss, o);
    int wid = t >> 6;
    if (u == 0) wsum[wid] = ss;
    __syncthreads();
    if (t == 0) {
        float tot = wsum[0] + wsum[1] + wsum[2] + wsum[3];
        sinv = 1.0f / fmaxf(sqrtf(tot), EPSF);
    }
    __syncthreads();
    const float sc = sinv * 0.125f;
    float2 o2; o2.x = v0 * sc; o2.y = v1 * sc;
    *(float2*)(out + (size_t)nk * CC + 2 * t) = o2;
}

extern "C" void kernel_launch(void* const* d_in, const int* in_sizes, int n_in,
                              void* d_out, int out_size, void* d_ws, size_t ws_size,
                              hipStream_t stream)
{
    const float* x    = (const float*)d_in[0];
    const float* w    = (const float*)d_in[1];
    const float* bias = (const float*)d_in[2];
    const float* cent = (const float*)d_in[3];
    float* out = (float*)d_out;

    char* ws = (char*)d_ws;
    size_t off = 0;
    unsigned short* ap  = (unsigned short*)(ws + off); off += (size_t)NN * KK * MM * 2;
    unsigned short* wb  = (unsigned short*)(ws + off); off += (size_t)KK * CC * 2;
    float* aggp      = (float*)(ws + off); off += (size_t)2 * NN * KK * CC * 4;
    float* asum_part = (float*)(ws + off); off += (size_t)NN * 25 * KK * 4;

    wconv_kernel <<<16, 256, 0, stream>>>(w, wb);
    fused1_kernel<<<dim3(25, 64), 256, 0, stream>>>(x, wb, bias, ap, asum_part);
    aggm_kernel  <<<dim3(8, 2, 64), 256, 0, stream>>>(x, ap, aggp);
    vlad_kernel  <<<NN * KK, 256, 0, stream>>>(aggp, asum_part, cent, out);
}

// Round 11
// 127.256 us; speedup vs baseline: 4.8409x; 4.8409x over previous
//
#include <hip/hip_runtime.h>
#include <hip/hip_bf16.h>

#define NN 64
#define CC 512
#define MM 1600
#define KK 64
#define EPSF 1e-12f

typedef __attribute__((ext_vector_type(4))) float f32x4;
typedef __attribute__((ext_vector_type(8))) short bf16x8;

// hardware RNE f32->bf16
__device__ inline unsigned short f2bf(float f) {
    __hip_bfloat16 b = __float2bfloat16(f);
    unsigned short u;
    __builtin_memcpy(&u, &b, sizeof(u));
    return u;
}

// ---------------------------------------------------------------------------
// w -> bf16
// ---------------------------------------------------------------------------
__global__ __launch_bounds__(256) void wconv_kernel(
    const float* __restrict__ w, unsigned short* __restrict__ wb)
{
    const int i = (blockIdx.x * 256 + threadIdx.x) * 8;
    float4 a = *(const float4*)(w + i);
    float4 b = *(const float4*)(w + i + 4);
    ushort4 u0, u1;
    u0.x = f2bf(a.x); u0.y = f2bf(a.y); u0.z = f2bf(a.z); u0.w = f2bf(a.w);
    u1.x = f2bf(b.x); u1.y = f2bf(b.y); u1.z = f2bf(b.z); u1.w = f2bf(b.w);
    *(ushort4*)(wb + i) = u0;
    *(ushort4*)(wb + i + 4) = u1;
}

// ---------------------------------------------------------------------------
// fused1 v3: per (n, 64-m tile). 2-deep pipelined scalar x loads -> bf16
// B-frag -> MFMA logits; shfl rnorm; register softmax; DIRECT ap stores from
// MFMA layout (no transpose LDS); asum via shfl + 1KB LDS. grid (25,64), 256.
// ---------------------------------------------------------------------------
__global__ __launch_bounds__(256) void fused1_kernel(
    const float* __restrict__ x, const unsigned short* __restrict__ wb,
    const float* __restrict__ bias,
    unsigned short* __restrict__ ap, float* __restrict__ asum_part)
{
    __shared__ float asum_l[4][64];

    const int t  = threadIdx.x;
    const int n  = blockIdx.y;
    const int mt = blockIdx.x;
    const int m0 = mt * 64;
    const int wv   = t >> 6;
    const int lane = t & 63;
    const int g    = lane >> 4;   // 0..3
    const int lr   = lane & 15;
    const int m_lane = m0 + wv * 16 + lr;

    f32x4 acc[4];
    #pragma unroll
    for (int kt = 0; kt < 4; ++kt) acc[kt] = (f32x4){0.f, 0.f, 0.f, 0.f};

    float ss = 0.f;
    const float* xcol = x + (size_t)n * CC * MM + m_lane;
    const unsigned short* wrow = wb + g * 8;

    // 2-deep software pipeline over 16 cs-batches (fully unrolled -> static regs)
    float xv[2][8];
    #pragma unroll
    for (int j = 0; j < 8; ++j) xv[0][j] = xcol[(size_t)(g * 8 + j) * MM];

    #pragma unroll
    for (int cs = 0; cs < 16; ++cs) {
        const int cur = cs & 1, nxt = cur ^ 1;
        if (cs < 15) {
            const int cbase = (cs + 1) * 32 + g * 8;
            #pragma unroll
            for (int j = 0; j < 8; ++j)
                xv[nxt][j] = xcol[(size_t)(cbase + j) * MM];
        }
        bf16x8 bfrag;
        #pragma unroll
        for (int j = 0; j < 8; ++j) {
            ss += xv[cur][j] * xv[cur][j];
            bfrag[j] = (short)f2bf(xv[cur][j]);
        }
        #pragma unroll
        for (int kt = 0; kt < 4; ++kt) {
            bf16x8 afrag = *(const bf16x8*)(wrow + (kt * 16 + lr) * CC + cs * 32);
            acc[kt] = __builtin_amdgcn_mfma_f32_16x16x32_bf16(afrag, bfrag, acc[kt], 0, 0, 0);
        }
    }

    // full sumsq for m_lane: reduce over the 4 g-slices
    ss += __shfl_xor(ss, 16);
    ss += __shfl_xor(ss, 32);
    const float rnm = 1.0f / fmaxf(sqrtf(ss), EPSF);

    // lane holds k = kt*16 + g*4 + r for its m_lane; softmax over k
    float l[16];
    #pragma unroll
    for (int kt = 0; kt < 4; ++kt) {
        float4 bb = *(const float4*)(bias + kt * 16 + g * 4);
        l[kt * 4 + 0] = acc[kt][0] * rnm + bb.x;
        l[kt * 4 + 1] = acc[kt][1] * rnm + bb.y;
        l[kt * 4 + 2] = acc[kt][2] * rnm + bb.z;
        l[kt * 4 + 3] = acc[kt][3] * rnm + bb.w;
    }
    float mx = l[0];
    #pragma unroll
    for (int i = 1; i < 16; ++i) mx = fmaxf(mx, l[i]);
    mx = fmaxf(mx, __shfl_xor(mx, 16));
    mx = fmaxf(mx, __shfl_xor(mx, 32));
    float s = 0.f;
    #pragma unroll
    for (int i = 0; i < 16; ++i) { l[i] = __expf(l[i] - mx); s += l[i]; }
    s += __shfl_xor(s, 16);
    s += __shfl_xor(s, 32);
    const float inv = 1.0f / s;

    // direct ap stores (a' = a*rnorm) + asum accumulation, no transpose LDS
    float a16[16];
    #pragma unroll
    for (int kt = 0; kt < 4; ++kt)
        #pragma unroll
        for (int r = 0; r < 4; ++r) {
            const float a = l[kt * 4 + r] * inv;
            a16[kt * 4 + r] = a;
            ap[((size_t)(n * KK + kt * 16 + g * 4 + r)) * MM + m_lane] = f2bf(a * rnm);
        }

    // asum: reduce over lr lanes (m within wave), then over 4 waves via LDS
    #pragma unroll
    for (int i = 0; i < 16; ++i) {
        a16[i] += __shfl_xor(a16[i], 1);
        a16[i] += __shfl_xor(a16[i], 2);
        a16[i] += __shfl_xor(a16[i], 4);
        a16[i] += __shfl_xor(a16[i], 8);
    }
    if (lr == 0) {
        #pragma unroll
        for (int kt = 0; kt < 4; ++kt)
            #pragma unroll
            for (int r = 0; r < 4; ++r)
                asum_l[wv][kt * 16 + g * 4 + r] = a16[kt * 4 + r];
    }
    __syncthreads();
    if (t < 64) {
        float sa = asum_l[0][t] + asum_l[1][t] + asum_l[2][t] + asum_l[3][t];
        asum_part[((size_t)(n * 25 + mt)) * 64 + t] = sa;
    }
}

// ---------------------------------------------------------------------------
// aggm: D[k64][c16/wave] = sum_m a'[k][m] * bf16(x[c][m]); x f32 strided from
// global (L2/L3-hot); ap staged via LDS with 1-deep register prefetch (T14).
// grid (8 ct, 2 mh, 64 n), block 256. Partial agg stores (2 m-halves).
// ---------------------------------------------------------------------------
__global__ __launch_bounds__(256) void aggm_kernel(
    const float* __restrict__ x, const unsigned short* __restrict__ ap,
    float* __restrict__ aggp)
{
    __shared__ __attribute__((aligned(16))) unsigned short als2[64][72];
    const int t    = threadIdx.x;
    const int ct   = blockIdx.x;
    const int mh   = blockIdx.y;
    const int n    = blockIdx.z;
    const int wv   = t >> 6;
    const int lane = t & 63;
    const int g    = lane >> 4;
    const int lr   = lane & 15;
    const int c_w  = ct * 64 + wv * 16;

    f32x4 acc[4];
    #pragma unroll
    for (int kt = 0; kt < 4; ++kt) acc[kt] = (f32x4){0.f, 0.f, 0.f, 0.f};

    const int ks = t >> 2, qs = t & 3;   // staging coords
    const float* xrow = x + ((size_t)(n * CC + c_w + lr)) * MM;
    const unsigned short* sbase = ap + ((size_t)(n * KK + ks)) * MM + qs * 16;

    const int mc_beg = mh ? 832 : 0;     // 13 tiles | 12 tiles
    const int mc_end = mh ? MM : 832;

    uint4 st0 = *(const uint4*)(sbase + mc_beg);
    uint4 st1 = *(const uint4*)(sbase + mc_beg + 8);

    for (int mc = mc_beg; mc < mc_end; mc += 64) {
        __syncthreads();
        *(uint4*)&als2[ks][qs * 16] = st0;
        *(uint4*)&als2[ks][qs * 16 + 8] = st1;
        __syncthreads();

        const int mn = mc + 64;
        if (mn < mc_end) {                 // prefetch next ap tile (hidden under MFMA)
            st0 = *(const uint4*)(sbase + mn);
            st1 = *(const uint4*)(sbase + mn + 8);
        }

        // hoist both msi x loads ahead of the MFMA cluster
        float4 v00 = *(const float4*)(xrow + mc + g * 8);
        float4 v01 = *(const float4*)(xrow + mc + g * 8 + 4);
        float4 v10 = *(const float4*)(xrow + mc + 32 + g * 8);
        float4 v11 = *(const float4*)(xrow + mc + 32 + g * 8 + 4);

        bf16x8 bf0;
        bf0[0] = (short)f2bf(v00.x); bf0[1] = (short)f2bf(v00.y);
        bf0[2] = (short)f2bf(v00.z); bf0[3] = (short)f2bf(v00.w);
        bf0[4] = (short)f2bf(v01.x); bf0[5] = (short)f2bf(v01.y);
        bf0[6] = (short)f2bf(v01.z); bf0[7] = (short)f2bf(v01.w);
        #pragma unroll
        for (int kt = 0; kt < 4; ++kt) {
            bf16x8 af = *(const bf16x8*)&als2[kt * 16 + lr][g * 8];
            acc[kt] = __builtin_amdgcn_mfma_f32_16x16x32_bf16(af, bf0, acc[kt], 0, 0, 0);
        }
        bf16x8 bf1;
        bf1[0] = (short)f2bf(v10.x); bf1[1] = (short)f2bf(v10.y);
        bf1[2] = (short)f2bf(v10.z); bf1[3] = (short)f2bf(v10.w);
        bf1[4] = (short)f2bf(v11.x); bf1[5] = (short)f2bf(v11.y);
        bf1[6] = (short)f2bf(v11.z); bf1[7] = (short)f2bf(v11.w);
        #pragma unroll
        for (int kt = 0; kt < 4; ++kt) {
            bf16x8 af = *(const bf16x8*)&als2[kt * 16 + lr][32 + g * 8];
            acc[kt] = __builtin_amdgcn_mfma_f32_16x16x32_bf16(af, bf1, acc[kt], 0, 0, 0);
        }
    }
    #pragma unroll
    for (int kt = 0; kt < 4; ++kt)
        #pragma unroll
        for (int r = 0; r < 4; ++r) {
            const int k = kt * 16 + g * 4 + r;
            aggp[((size_t)((mh * NN + n) * KK + k)) * CC + c_w + lr] = acc[kt][r];
        }
}

// ---------------------------------------------------------------------------
// vlad = (agg0+agg1) - asum*cent, intra-normalize over C, global scale 0.125
// (intra-normalized blocks have unit norm -> global norm = sqrt(64) = 8)
// ---------------------------------------------------------------------------
__global__ __launch_bounds__(256) void vlad_kernel(
    const float* __restrict__ aggp, const float* __restrict__ asum_part,
    const float* __restrict__ cent, float* __restrict__ out)
{
    __shared__ float wsum[4];
    __shared__ float sinv;
    const int nk = blockIdx.x;          // n*64 + k
    const int n = nk >> 6, k = nk & 63;
    const int t = threadIdx.x;
    const int u = t & 63;
    const size_t half = (size_t)NN * KK * CC;

    float pa = (u < 25) ? asum_part[((size_t)(n * 25 + u)) * 64 + k] : 0.f;
    #pragma unroll
    for (int o = 32; o > 0; o >>= 1) pa += __shfl_xor(pa, o);
    const float s = pa;

    float2 a0 = *(const float2*)(aggp + (size_t)nk * CC + 2 * t);
    float2 a1 = *(const float2*)(aggp + half + (size_t)nk * CC + 2 * t);
    float2 cv = *(const float2*)(cent + (size_t)k * CC + 2 * t);
    float v0 = (a0.x + a1.x) - s * cv.x;
    float v1 = (a0.y + a1.y) - s * cv.y;
    float ss = v0 * v0 + v1 * v1;
    #pragma unroll
    for (int o = 32; o > 0; o >>= 1) ss += __shfl_down(ss, o);
    int wid = t >> 6;
    if (u == 0) wsum[wid] = ss;
    __syncthreads();
    if (t == 0) {
        float tot = wsum[0] + wsum[1] + wsum[2] + wsum[3];
        sinv = 1.0f / fmaxf(sqrtf(tot), EPSF);
    }
    __syncthreads();
    const float sc = sinv * 0.125f;
    float2 o2; o2.x = v0 * sc; o2.y = v1 * sc;
    *(float2*)(out + (size_t)nk * CC + 2 * t) = o2;
}

extern "C" void kernel_launch(void* const* d_in, const int* in_sizes, int n_in,
                              void* d_out, int out_size, void* d_ws, size_t ws_size,
                              hipStream_t stream)
{
    const float* x    = (const float*)d_in[0];
    const float* w    = (const float*)d_in[1];
    const float* bias = (const float*)d_in[2];
    const float* cent = (const float*)d_in[3];
    float* out = (float*)d_out;

    char* ws = (char*)d_ws;
    size_t off = 0;
    unsigned short* ap  = (unsigned short*)(ws + off); off += (size_t)NN * KK * MM * 2;
    unsigned short* wb  = (unsigned short*)(ws + off); off += (size_t)KK * CC * 2;
    float* aggp      = (float*)(ws + off); off += (size_t)2 * NN * KK * CC * 4;
    float* asum_part = (float*)(ws + off); off += (size_t)NN * 25 * KK * 4;

    wconv_kernel <<<16, 256, 0, stream>>>(w, wb);
    fused1_kernel<<<dim3(25, 64), 256, 0, stream>>>(x, wb, bias, ap, asum_part);
    aggm_kernel  <<<dim3(8, 2, 64), 256, 0, stream>>>(x, ap, aggp);
    vlad_kernel  <<<NN * KK, 256, 0, stream>>>(aggp, asum_part, cent, out);
}

// Round 12
// 124.819 us; speedup vs baseline: 4.9354x; 1.0195x over previous
//
#include <hip/hip_runtime.h>
#include <hip/hip_bf16.h>

#define NN 64
#define CC 512
#define MM 1600
#define KK 64
#define EPSF 1e-12f
#define MT1 50   // fused1 m-tiles (32 m each)

typedef __attribute__((ext_vector_type(4))) float f32x4;
typedef __attribute__((ext_vector_type(8))) short bf16x8;

// hardware RNE f32->bf16
__device__ inline unsigned short f2bf(float f) {
    __hip_bfloat16 b = __float2bfloat16(f);
    unsigned short u;
    __builtin_memcpy(&u, &b, sizeof(u));
    return u;
}

// ---------------------------------------------------------------------------
// w -> bf16
// ---------------------------------------------------------------------------
__global__ __launch_bounds__(256) void wconv_kernel(
    const float* __restrict__ w, unsigned short* __restrict__ wb)
{
    const int i = (blockIdx.x * 256 + threadIdx.x) * 8;
    float4 a = *(const float4*)(w + i);
    float4 b = *(const float4*)(w + i + 4);
    ushort4 u0, u1;
    u0.x = f2bf(a.x); u0.y = f2bf(a.y); u0.z = f2bf(a.z); u0.w = f2bf(a.w);
    u1.x = f2bf(b.x); u1.y = f2bf(b.y); u1.z = f2bf(b.z); u1.w = f2bf(b.w);
    *(ushort4*)(wb + i) = u0;
    *(ushort4*)(wb + i + 4) = u1;
}

// ---------------------------------------------------------------------------
// fused1 v4: 32-m tiles, 128-thread (2-wave) blocks, grid (50, 64) = 3200
// blocks -> high resident-wave count to hide scalar-load latency.
// Per wave: 16 m, full K=64 logits MFMA over C=512; shfl rnorm; register
// softmax; LDS-transpose -> coalesced uint4 ap stores; asum partial per tile.
// ---------------------------------------------------------------------------
__global__ __launch_bounds__(128) void fused1_kernel(
    const float* __restrict__ x, const unsigned short* __restrict__ wb,
    const float* __restrict__ bias,
    unsigned short* __restrict__ ap, float* __restrict__ asum_part)
{
    __shared__ float als[64][34];   // a (unscaled), [k][m-tile 32]
    __shared__ float rn_s[32];

    const int t  = threadIdx.x;
    const int n  = blockIdx.y;
    const int mt = blockIdx.x;
    const int m0 = mt * 32;
    const int wv   = t >> 6;      // 0..1
    const int lane = t & 63;
    const int g    = lane >> 4;   // 0..3
    const int lr   = lane & 15;
    const int m_lane = m0 + wv * 16 + lr;

    f32x4 acc[4];
    #pragma unroll
    for (int kt = 0; kt < 4; ++kt) acc[kt] = (f32x4){0.f, 0.f, 0.f, 0.f};

    float ss = 0.f;
    const float* xcol = x + (size_t)n * CC * MM + m_lane;
    const unsigned short* wrow = wb + g * 8;

    #pragma unroll 4
    for (int cs = 0; cs < 16; ++cs) {
        const int cbase = cs * 32 + g * 8;
        float xv[8];
        #pragma unroll
        for (int j = 0; j < 8; ++j) xv[j] = xcol[(size_t)(cbase + j) * MM];
        bf16x8 bfrag;
        #pragma unroll
        for (int j = 0; j < 8; ++j) {
            ss += xv[j] * xv[j];
            bfrag[j] = (short)f2bf(xv[j]);
        }
        #pragma unroll
        for (int kt = 0; kt < 4; ++kt) {
            bf16x8 afrag = *(const bf16x8*)(wrow + (kt * 16 + lr) * CC + cs * 32);
            acc[kt] = __builtin_amdgcn_mfma_f32_16x16x32_bf16(afrag, bfrag, acc[kt], 0, 0, 0);
        }
    }

    // full sumsq for m_lane: reduce over the 4 g-slices
    ss += __shfl_xor(ss, 16);
    ss += __shfl_xor(ss, 32);
    const float rnm = 1.0f / fmaxf(sqrtf(ss), EPSF);
    if (g == 0) rn_s[wv * 16 + lr] = rnm;

    // lane holds k = kt*16 + g*4 + r for its m_lane; softmax over k
    float l[16];
    #pragma unroll
    for (int kt = 0; kt < 4; ++kt) {
        float4 bb = *(const float4*)(bias + kt * 16 + g * 4);
        l[kt * 4 + 0] = acc[kt][0] * rnm + bb.x;
        l[kt * 4 + 1] = acc[kt][1] * rnm + bb.y;
        l[kt * 4 + 2] = acc[kt][2] * rnm + bb.z;
        l[kt * 4 + 3] = acc[kt][3] * rnm + bb.w;
    }
    float mx = l[0];
    #pragma unroll
    for (int i = 1; i < 16; ++i) mx = fmaxf(mx, l[i]);
    mx = fmaxf(mx, __shfl_xor(mx, 16));
    mx = fmaxf(mx, __shfl_xor(mx, 32));
    float s = 0.f;
    #pragma unroll
    for (int i = 0; i < 16; ++i) { l[i] = __expf(l[i] - mx); s += l[i]; }
    s += __shfl_xor(s, 16);
    s += __shfl_xor(s, 32);
    const float inv = 1.0f / s;
    #pragma unroll
    for (int kt = 0; kt < 4; ++kt)
        #pragma unroll
        for (int r = 0; r < 4; ++r)
            als[kt * 16 + g * 4 + r][wv * 16 + lr] = l[kt * 4 + r] * inv;
    __syncthreads();

    // write a' = a*rnorm (bf16) row-wise (coalesced) + asum partial
    {
        const int k = t >> 1, half = t & 1;
        float spart = 0.f;
        unsigned short ub[16];
        #pragma unroll
        for (int i = 0; i < 16; ++i) {
            float a = als[k][half * 16 + i];
            spart += a;
            ub[i] = f2bf(a * rn_s[half * 16 + i]);
        }
        unsigned short* dst = ap + ((size_t)(n * KK + k)) * MM + m0 + half * 16;
        *(uint4*)dst = *(uint4*)&ub[0];
        *(uint4*)(dst + 8) = *(uint4*)&ub[8];
        spart += __shfl_xor(spart, 1);   // combine the two halves (t, t^1)
        if (half == 0) asum_part[((size_t)(n * MT1 + mt)) * 64 + k] = spart;
    }
}

// ---------------------------------------------------------------------------
// aggm (R8-proven): D[k64][c16/wave] = sum_m a'[k][m] * bf16(x[c][m]); x read
// f32 strided from global (L2/L3-hot), a' via LDS. grid (8 ct, 2 mh, 64 n),
// block 256. Partial agg stores (2 m-halves).
// ---------------------------------------------------------------------------
__global__ __launch_bounds__(256) void aggm_kernel(
    const float* __restrict__ x, const unsigned short* __restrict__ ap,
    float* __restrict__ aggp)
{
    __shared__ __attribute__((aligned(16))) unsigned short als2[64][72];
    const int t    = threadIdx.x;
    const int ct   = blockIdx.x;
    const int mh   = blockIdx.y;
    const int n    = blockIdx.z;
    const int wv   = t >> 6;
    const int lane = t & 63;
    const int g    = lane >> 4;
    const int lr   = lane & 15;
    const int c_w  = ct * 64 + wv * 16;

    f32x4 acc[4];
    #pragma unroll
    for (int kt = 0; kt < 4; ++kt) acc[kt] = (f32x4){0.f, 0.f, 0.f, 0.f};

    const int ks = t >> 2, qs = t & 3;   // staging coords
    const float* xrow = x + ((size_t)(n * CC + c_w + lr)) * MM;

    const int mc_beg = mh ? 832 : 0;     // 13 tiles | 12 tiles
    const int mc_end = mh ? MM : 832;

    for (int mc = mc_beg; mc < mc_end; mc += 64) {
        __syncthreads();
        {
            const unsigned short* src = ap + ((size_t)(n * KK + ks)) * MM + mc + qs * 16;
            uint4 w0 = *(const uint4*)src;
            uint4 w1 = *(const uint4*)(src + 8);
            *(uint4*)&als2[ks][qs * 16] = w0;
            *(uint4*)&als2[ks][qs * 16 + 8] = w1;
        }
        __syncthreads();
        #pragma unroll
        for (int msi = 0; msi < 2; ++msi) {
            const int ms = msi * 32;
            float4 v0 = *(const float4*)(xrow + mc + ms + g * 8);
            float4 v1 = *(const float4*)(xrow + mc + ms + g * 8 + 4);
            bf16x8 bf;
            bf[0] = (short)f2bf(v0.x); bf[1] = (short)f2bf(v0.y);
            bf[2] = (short)f2bf(v0.z); bf[3] = (short)f2bf(v0.w);
            bf[4] = (short)f2bf(v1.x); bf[5] = (short)f2bf(v1.y);
            bf[6] = (short)f2bf(v1.z); bf[7] = (short)f2bf(v1.w);
            #pragma unroll
            for (int kt = 0; kt < 4; ++kt) {
                bf16x8 af = *(const bf16x8*)&als2[kt * 16 + lr][ms + g * 8];
                acc[kt] = __builtin_amdgcn_mfma_f32_16x16x32_bf16(af, bf, acc[kt], 0, 0, 0);
            }
        }
    }
    #pragma unroll
    for (int kt = 0; kt < 4; ++kt)
        #pragma unroll
        for (int r = 0; r < 4; ++r) {
            const int k = kt * 16 + g * 4 + r;
            aggp[((size_t)((mh * NN + n) * KK + k)) * CC + c_w + lr] = acc[kt][r];
        }
}

// ---------------------------------------------------------------------------
// vlad = (agg0+agg1) - asum*cent, intra-normalize over C, global scale 0.125
// (intra-normalized blocks have unit norm -> global norm = sqrt(64) = 8)
// ---------------------------------------------------------------------------
__global__ __launch_bounds__(256) void vlad_kernel(
    const float* __restrict__ aggp, const float* __restrict__ asum_part,
    const float* __restrict__ cent, float* __restrict__ out)
{
    __shared__ float wsum[4];
    __shared__ float sinv;
    const int nk = blockIdx.x;          // n*64 + k
    const int n = nk >> 6, k = nk & 63;
    const int t = threadIdx.x;
    const int u = t & 63;
    const size_t half = (size_t)NN * KK * CC;

    // reduce asum over 50 m-tile partials (each wave redundantly)
    float pa = (u < MT1) ? asum_part[((size_t)(n * MT1 + u)) * 64 + k] : 0.f;
    #pragma unroll
    for (int o = 32; o > 0; o >>= 1) pa += __shfl_xor(pa, o);
    const float s = pa;

    float2 a0 = *(const float2*)(aggp + (size_t)nk * CC + 2 * t);
    float2 a1 = *(const float2*)(aggp + half + (size_t)nk * CC + 2 * t);
    float2 cv = *(const float2*)(cent + (size_t)k * CC + 2 * t);
    float v0 = (a0.x + a1.x) - s * cv.x;
    float v1 = (a0.y + a1.y) - s * cv.y;
    float ss = v0 * v0 + v1 * v1;
    #pragma unroll
    for (int o = 32; o > 0; o >>= 1) ss += __shfl_down(ss, o);
    int wid = t >> 6;
    if (u == 0) wsum[wid] = ss;
    __syncthreads();
    if (t == 0) {
        float tot = wsum[0] + wsum[1] + wsum[2] + wsum[3];
        sinv = 1.0f / fmaxf(sqrtf(tot), EPSF);
    }
    __syncthreads();
    const float sc = sinv * 0.125f;
    float2 o2; o2.x = v0 * sc; o2.y = v1 * sc;
    *(float2*)(out + (size_t)nk * CC + 2 * t) = o2;
}

extern "C" void kernel_launch(void* const* d_in, const int* in_sizes, int n_in,
                              void* d_out, int out_size, void* d_ws, size_t ws_size,
                              hipStream_t stream)
{
    const float* x    = (const float*)d_in[0];
    const float* w    = (const float*)d_in[1];
    const float* bias = (const float*)d_in[2];
    const float* cent = (const float*)d_in[3];
    float* out = (float*)d_out;

    char* ws = (char*)d_ws;
    size_t off = 0;
    unsigned short* ap  = (unsigned short*)(ws + off); off += (size_t)NN * KK * MM * 2;
    unsigned short* wb  = (unsigned short*)(ws + off); off += (size_t)KK * CC * 2;
    float* aggp      = (float*)(ws + off); off += (size_t)2 * NN * KK * CC * 4;
    float* asum_part = (float*)(ws + off); off += (size_t)NN * MT1 * KK * 4;

    wconv_kernel <<<16, 256, 0, stream>>>(w, wb);
    fused1_kernel<<<dim3(MT1, 64), 128, 0, stream>>>(x, wb, bias, ap, asum_part);
    aggm_kernel  <<<dim3(8, 2, 64), 256, 0, stream>>>(x, ap, aggp);
    vlad_kernel  <<<NN * KK, 256, 0, stream>>>(aggp, asum_part, cent, out);
}